// Round 2
// baseline (559.304 us; speedup 1.0000x reference)
//
#include <hip/hip_runtime.h>

// MoE conv: per-sample expert-selected 3x3 conv, fp32.
// x: [32, 64, 64, 64]  idx: [32] int  Wc: [4, 128, 64, 3, 3]  bc: [4, 128]
// out: [32, 128, 64, 64]
//
// Block = 256 threads: one sample, 64 output channels x (4 rows x 64 cols).
// Thread = 16 oc x 4 px register tile. IC chunked by 8 through LDS.

#define IC 64
#define OC 128
#define HH 64
#define WW 64
#define ICB 8
#define OC_TILE 64
#define ROWS 4

__global__ __launch_bounds__(256)
void moe_conv_kernel(const float* __restrict__ x, const int* __restrict__ idx,
                     const float* __restrict__ Wc, const float* __restrict__ bc,
                     float* __restrict__ out) {
    // x tile with halo: [ICB][6 rows][66 cols] (col 0 = global col -1 pad)
    __shared__ float xs[ICB * 6 * 66];
    // weights: [ICB][OC_TILE][12] (9 taps padded to 12 floats = 48B, 16B-aligned)
    __shared__ float ws[ICB * OC_TILE * 12];

    const int sp  = blockIdx.x;        // 0..15 spatial row-group
    const int ot  = blockIdx.y;        // 0..1 oc tile
    const int b   = blockIdx.z;        // 0..31 sample
    const int row0 = sp * ROWS;
    const int oc0  = ot * OC_TILE;
    // Clamp expert index: idempotent for valid values 0..3, and guarantees no
    // OOB address can ever be formed from this external value.
    const int e    = ((unsigned)idx[b]) & 3;

    const int t    = threadIdx.x;
    const int ocg  = t >> 6;           // 0..3 -> 16 oc each; wave-uniform
    const int pg   = t & 63;
    const int row  = pg >> 4;          // 0..3
    const int col4 = (pg & 15) << 2;   // 0,4,...,60

    const float* __restrict__ xb = x  + (size_t)b * IC * HH * WW;
    const float* __restrict__ wb = Wc + (size_t)e * OC * IC * 9;

    float acc[16][4];
#pragma unroll
    for (int o = 0; o < 16; ++o) {
        const float bv = bc[e * OC + oc0 + ocg * 16 + o];
#pragma unroll
        for (int p = 0; p < 4; ++p) acc[o][p] = bv;
    }

    for (int ic0 = 0; ic0 < IC; ic0 += ICB) {
        // ---- stage x tile (with zero halo) ----
        for (int j = t; j < ICB * 6 * 66; j += 256) {
            const int ic  = j / 396;           // 396 = 6*66
            const int rem = j - ic * 396;
            const int r   = rem / 66;
            const int c   = rem - r * 66;
            const int gh  = row0 + r - 1;
            const int gw  = c - 1;
            float v = 0.0f;
            if ((unsigned)gh < (unsigned)HH && (unsigned)gw < (unsigned)WW)
                v = xb[(ic0 + ic) * (HH * WW) + gh * WW + gw];
            xs[j] = v;
        }
        // ---- stage weights as [ic][oc][tap(pad 12)] ----
        for (int j = t; j < ICB * OC_TILE * 9; j += 256) {
            const int ic  = j / (OC_TILE * 9);
            const int rem = j - ic * (OC_TILE * 9);
            const int oc  = rem / 9;
            const int tp  = rem - oc * 9;
            ws[(ic * OC_TILE + oc) * 12 + tp] =
                wb[(oc0 + oc) * (IC * 9) + (ic0 + ic) * 9 + tp];
        }
        __syncthreads();

        // ---- compute ----
#pragma unroll
        for (int ic = 0; ic < ICB; ++ic) {
            float xv[3][6];
#pragma unroll
            for (int r = 0; r < 3; ++r)
#pragma unroll
                for (int c = 0; c < 6; ++c)
                    xv[r][c] = xs[(ic * 6 + row + r) * 66 + col4 + c];
#pragma unroll
            for (int o = 0; o < 16; ++o) {
                // weight base is (..)*12 floats = 48 B -> 16B-aligned: two
                // ds_read_b128 + one ds_read_b32 instead of 9 scalar reads.
                const float4* wp = (const float4*)&ws[(ic * OC_TILE + ocg * 16 + o) * 12];
                const float4 wA = wp[0];
                const float4 wB = wp[1];
                const float  w8 = ws[(ic * OC_TILE + ocg * 16 + o) * 12 + 8];
                const float wv[9] = {wA.x, wA.y, wA.z, wA.w, wB.x, wB.y, wB.z, wB.w, w8};
#pragma unroll
                for (int p = 0; p < 4; ++p)
#pragma unroll
                    for (int kh = 0; kh < 3; ++kh)
#pragma unroll
                        for (int kw = 0; kw < 3; ++kw)
                            acc[o][p] = fmaf(xv[kh][p + kw], wv[kh * 3 + kw], acc[o][p]);
            }
        }
        __syncthreads();
    }

    // ---- epilogue: coalesced float4 stores ----
#pragma unroll
    for (int o = 0; o < 16; ++o) {
        const int oc = oc0 + ocg * 16 + o;
        float4 v = make_float4(acc[o][0], acc[o][1], acc[o][2], acc[o][3]);
        *(float4*)(out + (((size_t)b * OC + oc) * HH + row0 + row) * WW + col4) = v;
    }
}

extern "C" void kernel_launch(void* const* d_in, const int* in_sizes, int n_in,
                              void* d_out, int out_size, void* d_ws, size_t ws_size,
                              hipStream_t stream) {
    const float* x   = (const float*)d_in[0];
    const int*   idx = (const int*)d_in[1];
    const float* Wc  = (const float*)d_in[2];
    const float* bc  = (const float*)d_in[3];
    float* out = (float*)d_out;

    dim3 grid(16, 2, 32);   // spatial x oc-tile x batch = 1024 blocks
    moe_conv_kernel<<<grid, 256, 0, stream>>>(x, idx, Wc, bc, out);
}

// Round 3
// 124.884 us; speedup vs baseline: 4.4786x; 4.4786x over previous
//
#include <hip/hip_runtime.h>
#include <hip/hip_bf16.h>

// MoE conv via bf16 MFMA implicit GEMM, tap-decomposed.
// x: [32,64,64,64] f32  idx: [32] i32  Wc: [4,128,64,3,3] f32  bc: [4,128] f32
// out: [32,128,64,64] f32
//
// Pre-kernel: Wc -> d_ws bf16, layout [e][tap][ich(8)][oc(128)][icl(8)] (576 KB).
// Main: block = 1 sample x 128 oc x (2 rows x 64 cols). 4 waves, each
// 64oc x 64pix = 2x2 accs of mfma_f32_32x32x16_bf16. x tile staged once as
// bf16 [r(4)][ich(8)][hc(66)][icl(8)]; weights per tap via global_load_lds.

#define IC 64
#define OC 128
#define HH 64
#define WW 64

typedef short short8 __attribute__((ext_vector_type(8)));
typedef float float16 __attribute__((ext_vector_type(16)));

static __device__ __forceinline__ ushort f2bf(float v) {
    __hip_bfloat16 h = __float2bfloat16(v);
    return *(ushort*)&h;
}

// ---------------- pre-kernel: reorder + convert weights ----------------
__global__ __launch_bounds__(256)
void reorder_w(const float* __restrict__ Wc, ushort* __restrict__ wout) {
    const int tid = blockIdx.x * 256 + threadIdx.x;   // (e*128+oc)*64+ic, 0..32767
    const int ic  = tid & 63;
    const int eoc = tid >> 6;
    const int oc  = eoc & 127;
    const int e   = eoc >> 7;
    const float* src = Wc + (size_t)tid * 9;          // contiguous 9 taps
    float v[9];
#pragma unroll
    for (int tp = 0; tp < 9; ++tp) v[tp] = src[tp];
#pragma unroll
    for (int tp = 0; tp < 9; ++tp)
        wout[((((size_t)e * 9 + tp) * 8 + (ic >> 3)) * 128 + oc) * 8 + (ic & 7)] = f2bf(v[tp]);
}

// ---------------- main kernel ----------------
__global__ __launch_bounds__(256)
void moe_conv_mfma(const float* __restrict__ x, const int* __restrict__ idx,
                   const ushort* __restrict__ wre, const float* __restrict__ bc,
                   float* __restrict__ out) {
    __shared__ __align__(16) ushort xs[4 * 8 * 66 * 8];  // [r][ich][hc][icl]
    __shared__ __align__(16) ushort wlds[8192];          // [ich][oc][icl]
    __shared__ float bias[128];

    const int t    = threadIdx.x;
    const int rp   = blockIdx.x;          // row pair 0..31
    const int b    = blockIdx.y;          // sample
    const int row0 = rp * 2;
    const int e    = ((unsigned)idx[b]) & 3;   // hardened expert index

    // --- halo-column zeros (hc = 0, 65) + bias stage ---
    if (t < 128) {
        const int r = t >> 5, ich = (t >> 2) & 7, side = (t >> 1) & 1, q = t & 1;
        const int hc = side ? 65 : 0;
        ushort4 z = {0, 0, 0, 0};
        *(ushort4*)&xs[(((r * 8 + ich) * 66 + hc) * 8 + q * 4)] = z;
    } else {
        bias[t - 128] = bc[e * 128 + (t - 128)];
    }

    // --- x staging: fp32 [ic][h][w] -> bf16 [r][ich][hc][icl], once per block ---
    const float* xb = x + (size_t)b * IC * HH * WW;
    {
        const int gc   = t & 63;     // coalesced lane = w
        const int csel = t >> 6;
        for (int it = 0; it < 16; ++it) {
            const int combo = it * 4 + csel;        // 0..63 = (r4, ich8, q2)
            const int r = combo >> 4, ich = (combo >> 1) & 7, q = combo & 1;
            const int gr = row0 - 1 + r;
            ushort4 u = {0, 0, 0, 0};
            if ((unsigned)gr < (unsigned)HH) {
                const int ic0 = ich * 8 + q * 4;
                u.x = f2bf(xb[((ic0 + 0) * HH + gr) * WW + gc]);
                u.y = f2bf(xb[((ic0 + 1) * HH + gr) * WW + gc]);
                u.z = f2bf(xb[((ic0 + 2) * HH + gr) * WW + gc]);
                u.w = f2bf(xb[((ic0 + 3) * HH + gr) * WW + gc]);
            }
            *(ushort4*)&xs[(((r * 8 + ich) * 66 + (gc + 1)) * 8 + q * 4)] = u;
        }
    }

    // --- per-lane MFMA coordinates ---
    const int l      = t & 63;
    const int lane31 = l & 31;
    const int lhi    = l >> 5;
    const int wv     = t >> 6;
    const int w0     = wv & 1;    // oc half
    const int pr     = wv >> 1;   // pixel row within pair

    float16 acc[2][2];
#pragma unroll
    for (int a = 0; a < 2; ++a)
#pragma unroll
        for (int cg = 0; cg < 2; ++cg)
#pragma unroll
            for (int r = 0; r < 16; ++r) acc[a][cg][r] = 0.0f;

    const ushort* wsrc = wre + (size_t)e * 9 * 8192;

    for (int tap = 0; tap < 9; ++tap) {
        __syncthreads();   // prior tap's reads done (tap 0: x/bias staging done)
        {
            const ushort* g0 = wsrc + tap * 8192;
#pragma unroll
            for (int i = 0; i < 4; ++i) {
                const int g = i * 256 + t;   // 16-B granule; lane-contiguous
                __builtin_amdgcn_global_load_lds(
                    (const __attribute__((address_space(1))) unsigned int*)(g0 + g * 8),
                    (__attribute__((address_space(3))) unsigned int*)&wlds[g * 8],
                    16, 0, 0);
            }
        }
        __syncthreads();   // vmcnt(0) drain -> wlds ready

        const int kh = tap / 3;
        const int kw = tap - kh * 3;
        const int rbase  = (pr + kh) * 8;        // (tile row)*8 in ich units
        const int hbase0 = lane31 + kw;          // halo col for cg=0

#pragma unroll
        for (int ks = 0; ks < 4; ++ks) {
            const int ich = ks * 2 + lhi;
            const short8 a0 = *(const short8*)&wlds[(ich * 128 + w0 * 64 + lane31) * 8];
            const short8 a1 = *(const short8*)&wlds[(ich * 128 + w0 * 64 + 32 + lane31) * 8];
            const short8 b0 = *(const short8*)&xs[((rbase + ich) * 66 + hbase0) * 8];
            const short8 b1 = *(const short8*)&xs[((rbase + ich) * 66 + hbase0 + 32) * 8];
            acc[0][0] = __builtin_amdgcn_mfma_f32_32x32x16_bf16(a0, b0, acc[0][0], 0, 0, 0);
            acc[0][1] = __builtin_amdgcn_mfma_f32_32x32x16_bf16(a0, b1, acc[0][1], 0, 0, 0);
            acc[1][0] = __builtin_amdgcn_mfma_f32_32x32x16_bf16(a1, b0, acc[1][0], 0, 0, 0);
            acc[1][1] = __builtin_amdgcn_mfma_f32_32x32x16_bf16(a1, b1, acc[1][1], 0, 0, 0);
        }
    }

    // --- epilogue: C/D layout col=lane&31, row=(reg&3)+8*(reg>>2)+4*(lane>>5) ---
#pragma unroll
    for (int a = 0; a < 2; ++a) {
        const int ocb = w0 * 64 + a * 32 + 4 * lhi;
#pragma unroll
        for (int reg = 0; reg < 16; ++reg) {
            const int oc = ocb + (reg & 3) + 8 * (reg >> 2);
            const float bv = bias[oc];
            const size_t base = (((size_t)b * OC + oc) * HH + (row0 + pr)) * WW;
            out[base + lane31]      = acc[a][0][reg] + bv;
            out[base + 32 + lane31] = acc[a][1][reg] + bv;
        }
    }
}

extern "C" void kernel_launch(void* const* d_in, const int* in_sizes, int n_in,
                              void* d_out, int out_size, void* d_ws, size_t ws_size,
                              hipStream_t stream) {
    const float* x   = (const float*)d_in[0];
    const int*   idx = (const int*)d_in[1];
    const float* Wc  = (const float*)d_in[2];
    const float* bc  = (const float*)d_in[3];
    float* out  = (float*)d_out;
    ushort* wre = (ushort*)d_ws;   // 294,912 bf16 = 576 KB scratch

    reorder_w<<<128, 256, 0, stream>>>(Wc, wre);
    dim3 grid(32, 32);             // row-pairs x samples = 1024 blocks
    moe_conv_mfma<<<grid, 256, 0, stream>>>(x, idx, wre, bc, out);
}

// Round 4
// 114.552 us; speedup vs baseline: 4.8825x; 1.0902x over previous
//
#include <hip/hip_runtime.h>
#include <hip/hip_bf16.h>

// MoE conv via bf16 MFMA implicit GEMM, tap-decomposed.
// x: [32,64,64,64] f32  idx: [32] i32  Wc: [4,128,64,3,3] f32  bc: [4,128] f32
// out: [32,128,64,64] f32
//
// Pre-kernel: 36 blocks (e,tap) -> d_ws bf16 [e][tap][ich(8)][oc(128)][icl(8)],
// coalesced ushort2 stores.
// Main: 512 threads = 8 waves: 1 sample x 128 oc x (4 rows x 64 cols).
// Wave = 64oc x 64px (one row): 2x2 accs of mfma_f32_32x32x16_bf16.
// LDS 67.6 KB -> 2 blocks/CU; grid 512 = exact full residency.

#define IC 64
#define OC 128
#define HH 64
#define WW 64

typedef short short8 __attribute__((ext_vector_type(8)));
typedef float float16 __attribute__((ext_vector_type(16)));

static __device__ __forceinline__ ushort f2bf(float v) {
    __hip_bfloat16 h = __float2bfloat16(v);
    return *(ushort*)&h;
}

// ---------------- pre-kernel: reorder + convert weights ----------------
// block = one (expert, tap); output 16 KB contiguous, ushort2-coalesced.
__global__ __launch_bounds__(256)
void reorder_w(const float* __restrict__ Wc, ushort* __restrict__ wout) {
    const int blk = blockIdx.x;            // e*9 + tap
    const int e   = blk / 9;
    const int tap = blk - e * 9;
    const float* __restrict__ src = Wc + (size_t)e * OC * IC * 9 + tap;
    ushort2* __restrict__ dst = (ushort2*)(wout + (size_t)blk * 8192);
    for (int j = threadIdx.x; j < 4096; j += 256) {
        const int ich = j >> 9;            // 0..7
        const int oc  = (j >> 2) & 127;
        const int ip  = j & 3;             // icl pair
        const int ic  = ich * 8 + ip * 2;
        const float v0 = src[(oc * IC + ic) * 9];
        const float v1 = src[(oc * IC + ic + 1) * 9];
        ushort2 u;
        u.x = f2bf(v0);
        u.y = f2bf(v1);
        dst[j] = u;                        // lanes contiguous -> coalesced
    }
}

// ---------------- main kernel ----------------
__global__ __launch_bounds__(512)
void moe_conv_mfma(const float* __restrict__ x, const int* __restrict__ idx,
                   const ushort* __restrict__ wre, const float* __restrict__ bc,
                   float* __restrict__ out) {
    __shared__ __align__(16) ushort xs[6 * 8 * 66 * 8];  // [r][ich][hc][icl] 50688 B
    __shared__ __align__(16) ushort wlds[8192];          // [ich][oc][icl] 16 KB
    __shared__ float bias[128];

    const int t    = threadIdx.x;
    const int rq   = blockIdx.x;          // row quad 0..15
    const int b    = blockIdx.y;          // sample
    const int row0 = rq * 4;
    const int e    = ((unsigned)idx[b]) & 3;   // hardened expert index

    // --- halo-column zeros (hc = 0, 65) + bias stage ---
    if (t < 192) {  // r(6) x ich(8) x side(2) x q(2)
        const int r = t >> 5, rem = t & 31;
        const int ich = rem >> 2, side = (rem >> 1) & 1, q = rem & 1;
        const int hc = side ? 65 : 0;
        ushort4 z = {0, 0, 0, 0};
        *(ushort4*)&xs[(((r * 8 + ich) * 66 + hc) * 8 + q * 4)] = z;
    } else if (t < 320) {
        bias[t - 192] = bc[e * OC + (t - 192)];
    }

    // --- x staging: fp32 [ic][h][w] -> bf16 [r(6)][ich][hc][icl] ---
    const float* xb = x + (size_t)b * IC * HH * WW;
    {
        const int gc   = t & 63;          // coalesced lane = w
        const int csel = t >> 6;          // 0..7
#pragma unroll
        for (int it = 0; it < 12; ++it) {
            const int combo = it * 8 + csel;       // 0..95 = r(6) x ich(8) x q(2)
            const int r = combo >> 4, rem = combo & 15;
            const int ich = rem >> 1, q = rem & 1;
            const int gr = row0 - 1 + r;
            ushort4 u = {0, 0, 0, 0};
            if ((unsigned)gr < (unsigned)HH) {
                const int ic0 = ich * 8 + q * 4;
                u.x = f2bf(xb[((ic0 + 0) * HH + gr) * WW + gc]);
                u.y = f2bf(xb[((ic0 + 1) * HH + gr) * WW + gc]);
                u.z = f2bf(xb[((ic0 + 2) * HH + gr) * WW + gc]);
                u.w = f2bf(xb[((ic0 + 3) * HH + gr) * WW + gc]);
            }
            *(ushort4*)&xs[(((r * 8 + ich) * 66 + (gc + 1)) * 8 + q * 4)] = u;
        }
    }

    // --- per-lane MFMA coordinates ---
    const int lane31 = t & 31;
    const int lhi    = (t >> 5) & 1;
    const int wv     = t >> 6;            // 0..7
    const int w0     = wv & 1;            // oc half
    const int pr     = wv >> 1;           // output row within quad, 0..3

    float16 acc[2][2];
#pragma unroll
    for (int a = 0; a < 2; ++a)
#pragma unroll
        for (int cg = 0; cg < 2; ++cg)
#pragma unroll
            for (int r = 0; r < 16; ++r) acc[a][cg][r] = 0.0f;

    const ushort* wsrc = wre + (size_t)e * 9 * 8192;

    for (int tap = 0; tap < 9; ++tap) {
        __syncthreads();   // prior tap's wlds reads done (tap 0: no-op ordering)
        {
            const ushort* g0 = wsrc + tap * 8192;
#pragma unroll
            for (int i = 0; i < 2; ++i) {
                const int g = i * 512 + t;   // 16-B granule; lane-contiguous
                __builtin_amdgcn_global_load_lds(
                    (const __attribute__((address_space(1))) unsigned int*)(g0 + g * 8),
                    (__attribute__((address_space(3))) unsigned int*)&wlds[g * 8],
                    16, 0, 0);
            }
        }
        __syncthreads();   // drains vmcnt -> wlds ready; also covers x staging

        const int kh = tap / 3;
        const int kw = tap - kh * 3;
        const int rr = pr + kh;              // staged row 0..5
        const int hb = lane31 + kw;          // halo col for cg=0

#pragma unroll
        for (int ks = 0; ks < 4; ++ks) {
            const int ich = ks * 2 + lhi;
            const short8 a0 = *(const short8*)&wlds[(ich * 128 + w0 * 64 + lane31) * 8];
            const short8 a1 = *(const short8*)&wlds[(ich * 128 + w0 * 64 + 32 + lane31) * 8];
            const short8 b0 = *(const short8*)&xs[((rr * 8 + ich) * 66 + hb) * 8];
            const short8 b1 = *(const short8*)&xs[((rr * 8 + ich) * 66 + hb + 32) * 8];
            acc[0][0] = __builtin_amdgcn_mfma_f32_32x32x16_bf16(a0, b0, acc[0][0], 0, 0, 0);
            acc[0][1] = __builtin_amdgcn_mfma_f32_32x32x16_bf16(a0, b1, acc[0][1], 0, 0, 0);
            acc[1][0] = __builtin_amdgcn_mfma_f32_32x32x16_bf16(a1, b0, acc[1][0], 0, 0, 0);
            acc[1][1] = __builtin_amdgcn_mfma_f32_32x32x16_bf16(a1, b1, acc[1][1], 0, 0, 0);
        }
    }

    // --- epilogue: C/D layout col=lane&31, row=(reg&3)+8*(reg>>2)+4*(lane>>5) ---
#pragma unroll
    for (int a = 0; a < 2; ++a) {
        const int ocb = w0 * 64 + a * 32 + 4 * lhi;
#pragma unroll
        for (int reg = 0; reg < 16; ++reg) {
            const int oc = ocb + (reg & 3) + 8 * (reg >> 2);
            const float bv = bias[oc];
            const size_t base = (((size_t)b * OC + oc) * HH + (row0 + pr)) * WW;
            out[base + lane31]      = acc[a][0][reg] + bv;
            out[base + 32 + lane31] = acc[a][1][reg] + bv;
        }
    }
}

extern "C" void kernel_launch(void* const* d_in, const int* in_sizes, int n_in,
                              void* d_out, int out_size, void* d_ws, size_t ws_size,
                              hipStream_t stream) {
    const float* x   = (const float*)d_in[0];
    const int*   idx = (const int*)d_in[1];
    const float* Wc  = (const float*)d_in[2];
    const float* bc  = (const float*)d_in[3];
    float* out  = (float*)d_out;
    ushort* wre = (ushort*)d_ws;   // 294,912 bf16 = 576 KB scratch

    reorder_w<<<36, 256, 0, stream>>>(Wc, wre);
    dim3 grid(16, 32);             // row-quads x samples = 512 blocks
    moe_conv_mfma<<<grid, 512, 0, stream>>>(x, idx, wre, bc, out);
}

// Round 7
// 110.261 us; speedup vs baseline: 5.0726x; 1.0389x over previous
//
#include <hip/hip_runtime.h>
#include <hip/hip_bf16.h>

// MoE conv via bf16 MFMA implicit GEMM, tap-decomposed.
// x: [32,64,64,64] f32  idx: [32] i32  Wc: [4,128,64,3,3] f32 (294,912 floats
// TOTAL, 73,728 per expert — R4/R5 used 4x this and faulted)  bc: [4,128] f32
// out: [32,128,64,64] f32
//
// Pre-kernel: linear transpose Wc -> d_ws bf16 [e][tap][ich(8)][oc(128)][icl(8)]
// (576 KB), 1152x256, one coalesced 4B read + one scattered 2B store per thread.
// Main: 512 threads = 8 waves: 1 sample x 128 oc x (4 rows x 64 cols).
// Wave = 64oc x 64px (one row): 2x2 accs of mfma_f32_32x32x16_bf16.
// Per-tap weights double-buffered through 32 B of VGPRs per thread so tap k+1's
// global loads fly under tap k's MFMAs (no per-tap vmcnt(0) drain).
// LDS 67.7 KB -> 2 blocks/CU; grid 512 = exact full residency.

#define IC 64
#define OC 128
#define HH 64
#define WW 64

typedef short short8 __attribute__((ext_vector_type(8)));
typedef float float16 __attribute__((ext_vector_type(16)));

static __device__ __forceinline__ ushort f2bf(float v) {
    __hip_bfloat16 h = __float2bfloat16(v);
    return *(ushort*)&h;
}

// ---------------- pre-kernel: reorder + convert weights ----------------
// One element per thread, n linear over Wc's 294,912 floats (coalesced reads).
// Wc flat index: ((e*128 + oc)*64 + ic)*9 + tap.
__global__ __launch_bounds__(256)
void reorder_w(const float* __restrict__ Wc, ushort* __restrict__ wout) {
    const int n = blockIdx.x * 256 + threadIdx.x;   // 0 .. 294,911
    const float v = Wc[n];
    const int e  = n / 73728;                       // 128*64*9
    int r        = n - e * 73728;
    const int oc = r / 576;                         // 64*9
    r           -= oc * 576;
    const int ic  = r / 9;
    const int tap = r - ic * 9;
    wout[((((size_t)e * 9 + tap) * 8 + (ic >> 3)) * 128 + oc) * 8 + (ic & 7)] =
        f2bf(v);
}

// ---------------- main kernel ----------------
__global__ __launch_bounds__(512)
void moe_conv_mfma(const float* __restrict__ x, const int* __restrict__ idx,
                   const ushort* __restrict__ wre, const float* __restrict__ bc,
                   float* __restrict__ out) {
    __shared__ __align__(16) ushort xs[6 * 8 * 66 * 8];  // [r][ich][hc][icl] 50688 B
    __shared__ __align__(16) ushort wlds[8192];          // [ich][oc][icl] 16 KB
    __shared__ float bias[128];

    const int t    = threadIdx.x;
    const int rq   = blockIdx.x;          // row quad 0..15
    const int b    = blockIdx.y;          // sample
    const int row0 = rq * 4;
    const int e    = ((unsigned)idx[b]) & 3;   // hardened expert index

    // --- halo-column zeros (hc = 0, 65) + bias stage ---
    if (t < 192) {  // r(6) x ich(8) x side(2) x q(2)
        const int r = t >> 5, rem = t & 31;
        const int ich = rem >> 2, side = (rem >> 1) & 1, q = rem & 1;
        const int hc = side ? 65 : 0;
        ushort4 z = {0, 0, 0, 0};
        *(ushort4*)&xs[(((r * 8 + ich) * 66 + hc) * 8 + q * 4)] = z;
    } else if (t < 320) {
        bias[t - 192] = bc[e * OC + (t - 192)];
    }

    // --- x staging: fp32 [ic][h][w] -> bf16 [r(6)][ich][hc][icl] ---
    const float* xb = x + (size_t)b * IC * HH * WW;
    {
        const int gc   = t & 63;          // coalesced lane = w
        const int csel = t >> 6;          // 0..7
#pragma unroll
        for (int it = 0; it < 12; ++it) {
            const int combo = it * 8 + csel;       // 0..95 = r(6) x ich(8) x q(2)
            const int r = combo >> 4, rem = combo & 15;
            const int ich = rem >> 1, q = rem & 1;
            const int gr = row0 - 1 + r;
            ushort4 u = {0, 0, 0, 0};
            if ((unsigned)gr < (unsigned)HH) {
                const int ic0 = ich * 8 + q * 4;
                u.x = f2bf(xb[((ic0 + 0) * HH + gr) * WW + gc]);
                u.y = f2bf(xb[((ic0 + 1) * HH + gr) * WW + gc]);
                u.z = f2bf(xb[((ic0 + 2) * HH + gr) * WW + gc]);
                u.w = f2bf(xb[((ic0 + 3) * HH + gr) * WW + gc]);
            }
            *(ushort4*)&xs[(((r * 8 + ich) * 66 + (gc + 1)) * 8 + q * 4)] = u;
        }
    }

    // --- per-lane MFMA coordinates ---
    const int lane31 = t & 31;
    const int lhi    = (t >> 5) & 1;
    const int wv     = t >> 6;            // 0..7
    const int w0     = wv & 1;            // oc half
    const int pr     = wv >> 1;           // output row within quad, 0..3

    float16 acc[2][2];
#pragma unroll
    for (int a = 0; a < 2; ++a)
#pragma unroll
        for (int cg = 0; cg < 2; ++cg)
#pragma unroll
            for (int r = 0; r < 16; ++r) acc[a][cg][r] = 0.0f;

    const ushort* wsrc = wre + (size_t)e * 9 * 8192;   // e-slice: 73,728 bf16

    // --- register prefetch of tap 0's weights (16 KB / 512 thr = 32 B) ---
    uint4 wreg0, wreg1;
    {
        const uint4* g = (const uint4*)wsrc;
        wreg0 = g[t];
        wreg1 = g[512 + t];
    }

    for (int tap = 0; tap < 9; ++tap) {
        __syncthreads();   // prior tap's wlds reads done (tap 0: covers xs/bias)
        // commit prefetched weights (lane-contiguous 16 B -> conflict-free)
        *(uint4*)&wlds[(size_t)t * 8]         = wreg0;
        *(uint4*)&wlds[(size_t)(512 + t) * 8] = wreg1;
        __syncthreads();   // wlds visible
        if (tap < 8) {     // issue tap+1 loads; they fly under the MFMAs below
            const uint4* g = (const uint4*)(wsrc + (tap + 1) * 8192);
            wreg0 = g[t];          // max uint4 index: 3*9216 + 9215 = 36863 ✓
            wreg1 = g[512 + t];
        }

        const int kh = tap / 3;
        const int kw = tap - kh * 3;
        const int rr = pr + kh;              // staged row 0..5
        const int hb = lane31 + kw;          // halo col for cg=0

#pragma unroll
        for (int ks = 0; ks < 4; ++ks) {
            const int ich = ks * 2 + lhi;
            const short8 a0 = *(const short8*)&wlds[(ich * 128 + w0 * 64 + lane31) * 8];
            const short8 a1 = *(const short8*)&wlds[(ich * 128 + w0 * 64 + 32 + lane31) * 8];
            const short8 b0 = *(const short8*)&xs[((rr * 8 + ich) * 66 + hb) * 8];
            const short8 b1 = *(const short8*)&xs[((rr * 8 + ich) * 66 + hb + 32) * 8];
            acc[0][0] = __builtin_amdgcn_mfma_f32_32x32x16_bf16(a0, b0, acc[0][0], 0, 0, 0);
            acc[0][1] = __builtin_amdgcn_mfma_f32_32x32x16_bf16(a0, b1, acc[0][1], 0, 0, 0);
            acc[1][0] = __builtin_amdgcn_mfma_f32_32x32x16_bf16(a1, b0, acc[1][0], 0, 0, 0);
            acc[1][1] = __builtin_amdgcn_mfma_f32_32x32x16_bf16(a1, b1, acc[1][1], 0, 0, 0);
        }
    }

    // --- epilogue: C/D layout col=lane&31, row=(reg&3)+8*(reg>>2)+4*(lane>>5) ---
#pragma unroll
    for (int a = 0; a < 2; ++a) {
        const int ocb = w0 * 64 + a * 32 + 4 * lhi;
#pragma unroll
        for (int reg = 0; reg < 16; ++reg) {
            const int oc = ocb + (reg & 3) + 8 * (reg >> 2);
            const float bv = bias[oc];
            const size_t base = (((size_t)b * OC + oc) * HH + (row0 + pr)) * WW;
            out[base + lane31]      = acc[a][0][reg] + bv;
            out[base + 32 + lane31] = acc[a][1][reg] + bv;
        }
    }
}

extern "C" void kernel_launch(void* const* d_in, const int* in_sizes, int n_in,
                              void* d_out, int out_size, void* d_ws, size_t ws_size,
                              hipStream_t stream) {
    const float* x   = (const float*)d_in[0];
    const int*   idx = (const int*)d_in[1];
    const float* Wc  = (const float*)d_in[2];
    const float* bc  = (const float*)d_in[3];
    float* out  = (float*)d_out;
    ushort* wre = (ushort*)d_ws;   // 294,912 bf16 = 576 KB scratch

    reorder_w<<<1152, 256, 0, stream>>>(Wc, wre);   // 1152*256 = 294,912 = |Wc|
    dim3 grid(16, 32);             // row-quads x samples = 512 blocks
    moe_conv_mfma<<<grid, 512, 0, stream>>>(x, idx, wre, bc, out);
}